// Round 5
// baseline (524.511 us; speedup 1.0000x reference)
//
#include <hip/hip_runtime.h>

#define LDA 136   // padded B LDS row stride (bf16 elems)
#define TM  64    // atoms per tile

// W3J112 constant (3,3,5), already divided by sqrt(5). idx = i*15 + j*5 + k
__constant__ float W3J[45] = {
  0.f, 0.f, -0.18257418583505536f, 0.f, -0.31622776601683794f,
  0.f, 0.31622776601683794f, 0.f, 0.f, 0.f,
  0.31622776601683794f, 0.f, 0.f, 0.f, 0.f,
  0.f, 0.31622776601683794f, 0.f, 0.f, 0.f,
  0.f, 0.f, 0.36514837167011072f, 0.f, 0.f,
  0.f, 0.f, 0.f, 0.31622776601683794f, 0.f,
  0.31622776601683794f, 0.f, 0.f, 0.f, 0.f,
  0.f, 0.f, 0.f, 0.31622776601683794f, 0.f,
  0.f, 0.f, -0.18257418583505536f, 0.f, 0.31622776601683794f
};

__device__ __forceinline__ unsigned short f2bf(float f) {
  unsigned int u = __float_as_uint(f);
  u += 0x7FFFu + ((u >> 16) & 1u);   // round-to-nearest-even
  return (unsigned short)(u >> 16);
}

// Build Bt[n][k] = M[k][n] in bf16, padded to 128x128 with zeros.
// out[z,n] = sum_k geom[z,k] * M[k][n]
__global__ void build_B_kernel(
    const float* __restrict__ field,
    const float* __restrict__ w000, const float* __restrict__ w011,
    const float* __restrict__ w101, const float* __restrict__ w110,
    const float* __restrict__ w112, const float* __restrict__ w202,
    const float* __restrict__ w211, const float* __restrict__ wl0,
    const float* __restrict__ wl1,  const float* __restrict__ wl2,
    unsigned short* __restrict__ Bt)
{
  const float C0  = 0.02795084971874737f;   // sqrt(1/1280)
  const float C1  = 0.051031036307982884f;  // sqrt(3/1152)
  const float C2  = 0.09882117688026186f;   // sqrt(5/512)
  const float IS3 = 0.57735026918962576f;
  const float IS5 = 0.44721359549995794f;

  int n = blockIdx.x;    // output col 0..127
  int k = threadIdx.x;   // input row  0..127
  float val = 0.0f;

  if (n < 120 && k < 120) {
    if (n < 32) {
      int w = n;
      if (k < 32) {                 // g0 -> out0
        int u = k;
        float a = 0.f;
        for (int v = 0; v < 32; ++v) a += w000[u*1024 + v*32 + w] * field[v];
        val = C0 * a + wl0[u*32 + w] * 0.17677669529663689f;
      } else if (k < 80) {          // g1 -> out0 (110)
        int u = (k-32)/3, i = (k-32)%3;
        float a = 0.f;
        for (int v = 0; v < 16; ++v) a += w110[u*512 + v*32 + w] * field[32 + v*3 + i];
        val = C0 * IS3 * a;
      }                             // g2 -> out0 : zero
    } else if (n < 80) {
      int w = (n-32)/3, j = (n-32)%3;
      if (k < 32) {                 // g0 -> out1 (011)
        int u = k;
        float a = 0.f;
        for (int v = 0; v < 16; ++v) a += w011[u*256 + v*16 + w] * field[32 + v*3 + j];
        val = C1 * IS3 * a;
      } else if (k < 80) {          // g1 -> out1 (101 + residual), spatial-diagonal
        int u = (k-32)/3, i = (k-32)%3;
        if (i == j) {
          float a = 0.f;
          for (int v = 0; v < 32; ++v) a += w101[u*512 + v*16 + w] * field[v];
          val = C1 * IS3 * a + wl1[u*16 + w] * 0.25f;
        }
      } else {                      // g2 -> out1 (211 x W3J)
        int u = (k-80)/5, kk = (k-80)%5;
        float c0w = W3J[0*15 + j*5 + kk];
        float c1w = W3J[1*15 + j*5 + kk];
        float c2w = W3J[2*15 + j*5 + kk];
        float a = 0.f;
        for (int v = 0; v < 16; ++v) {
          float s = c0w*field[32+v*3+0] + c1w*field[32+v*3+1] + c2w*field[32+v*3+2];
          a += w211[u*256 + v*16 + w] * s;
        }
        val = C1 * a;
      }
    } else {
      int w = (n-80)/5, k2 = (n-80)%5;
      if (k >= 32 && k < 80) {      // g1 -> out2 (112 x W3J)
        int u = (k-32)/3, i = (k-32)%3;
        float c0w = W3J[i*15 + 0*5 + k2];
        float c1w = W3J[i*15 + 1*5 + k2];
        float c2w = W3J[i*15 + 2*5 + k2];
        float a = 0.f;
        for (int v = 0; v < 16; ++v) {
          float s = c0w*field[32+v*3+0] + c1w*field[32+v*3+1] + c2w*field[32+v*3+2];
          a += w112[u*128 + v*8 + w] * s;
        }
        val = C2 * a;
      } else if (k >= 80) {         // g2 -> out2 (202 + residual), spatial-diagonal
        int u = (k-80)/5, kk = (k-80)%5;
        if (kk == k2) {
          float a = 0.f;
          for (int v = 0; v < 32; ++v) a += w202[u*256 + v*8 + w] * field[v];
          val = C2 * IS5 * a + wl2[u*8 + w] * 0.35355339059327378f;
        }
      }                             // g0 -> out2 : zero
    }
  }
  Bt[n*128 + k] = f2bf(val);
}

typedef __attribute__((ext_vector_type(8))) __bf16 bf16x8;
typedef __attribute__((ext_vector_type(4))) float  f32x4;

// out(500000x120) = geom(500000x120) @ M(120x120), bf16 MFMA 16x16x32, fp32 accum.
// v4: PERSISTENT blocks (grid = 4/CU x 256 CU). B staged to LDS ONCE per block;
//     tile loop has NO barriers: convert A(cur) -> issue A-loads(next) -> MFMA -> store.
//     Next-tile HBM loads are always in flight under current-tile compute (1-deep pipeline).
__global__ __launch_bounds__(256, 4) void coupling_main(
    const float* __restrict__ geom, const unsigned short* __restrict__ Btg,
    float* __restrict__ out, int natoms, int ntiles)
{
  __shared__ alignas(16) unsigned short Bl[128 * LDA];   // 34816 B

  const int tid  = threadIdx.x;
  const int lane = tid & 63;
  const int wave = tid >> 6;
  const int mrow = lane & 15;   // A row / B col within 16-tile
  const int kq   = lane >> 4;   // k-quad

  // stage B (128x128 bf16) into LDS once; L2-hot across blocks
  #pragma unroll
  for (int r = 0; r < 8; ++r) {
    int g   = tid + r * 256;        // 0..2047 groups of 8 bf16
    int row = g >> 4;
    int col = (g & 15) * 8;
    uint4 v = ((const uint4*)Btg)[g];
    *((uint4*)&Bl[row * LDA + col]) = v;
  }

  const int rowin = wave * 16 + mrow;   // row within tile, 0..63
  int tile = blockIdx.x;
  const int stride = gridDim.x;
  const float4 f0 = make_float4(0.f, 0.f, 0.f, 0.f);

  float4 alo[4], ahi[4];

  // prefetch A for first tile (in flight across the B barrier)
  if (tile < ntiles) {
    long long atom = (long long)tile * TM + rowin;
    const float* ga = geom + atom * 120 + kq * 8;
    bool full = ((long long)tile * TM + TM) <= natoms;
    bool ina  = full || (atom < natoms);
    #pragma unroll
    for (int ks = 0; ks < 4; ++ks) {
      bool pad = (ks == 3) && (kq == 3);   // k = 120..127 -> zero
      if (ina && !pad) {
        alo[ks] = ((const float4*)(ga + ks * 32))[0];
        ahi[ks] = ((const float4*)(ga + ks * 32))[1];
      } else {
        alo[ks] = f0; ahi[ks] = f0;
      }
    }
  } else {
    #pragma unroll
    for (int ks = 0; ks < 4; ++ks) { alo[ks] = f0; ahi[ks] = f0; }
  }

  __syncthreads();   // B tile visible

  const unsigned short* brow = &Bl[mrow * LDA + kq * 8];

  while (tile < ntiles) {
    const int next = tile + stride;
    const long long tbase = (long long)tile * TM;

    // convert current A payload to bf16 fragments (dependency-waits on its loads)
    bf16x8 af[4];
    #pragma unroll
    for (int ks = 0; ks < 4; ++ks) {
      uint4 pk;
      pk.x = ((unsigned)f2bf(alo[ks].y) << 16) | f2bf(alo[ks].x);
      pk.y = ((unsigned)f2bf(alo[ks].w) << 16) | f2bf(alo[ks].z);
      pk.z = ((unsigned)f2bf(ahi[ks].y) << 16) | f2bf(ahi[ks].x);
      pk.w = ((unsigned)f2bf(ahi[ks].w) << 16) | f2bf(ahi[ks].z);
      af[ks] = __builtin_bit_cast(bf16x8, pk);
    }

    // issue next-tile prefetch NOW; lands under this tile's MFMA + stores
    if (next < ntiles) {
      long long atom = (long long)next * TM + rowin;
      const float* ga = geom + atom * 120 + kq * 8;
      bool full = ((long long)next * TM + TM) <= natoms;
      bool ina  = full || (atom < natoms);
      #pragma unroll
      for (int ks = 0; ks < 4; ++ks) {
        bool pad = (ks == 3) && (kq == 3);
        if (ina && !pad) {
          alo[ks] = ((const float4*)(ga + ks * 32))[0];
          ahi[ks] = ((const float4*)(ga + ks * 32))[1];
        } else {
          alo[ks] = f0; ahi[ks] = f0;
        }
      }
    }

    // MFMA: 4 k-steps x 8 col-tiles, B from LDS (lgkmcnt fine-scheduled)
    f32x4 acc[8];
    #pragma unroll
    for (int t = 0; t < 8; ++t) acc[t] = (f32x4){0.f, 0.f, 0.f, 0.f};
    #pragma unroll
    for (int ks = 0; ks < 4; ++ks) {
      #pragma unroll
      for (int t = 0; t < 8; ++t) {
        bf16x8 bf_ = __builtin_bit_cast(bf16x8, *(const uint4*)(brow + t * 16 * LDA + ks * 32));
        acc[t] = __builtin_amdgcn_mfma_f32_16x16x32_bf16(af[ks], bf_, acc[t], 0, 0, 0);
      }
    }

    // store direct from acc (C/D layout: col = lane&15, row = (lane>>4)*4 + reg)
    // per (t,r2) instruction: 4 atoms x 64 B contiguous segments — L2-merged (cost-equal to
    // the LDS-transposed float4 path, measured v0 == v3)
    long long atom0 = tbase + wave * 16 + kq * 4;
    if (tbase + TM <= natoms) {
      #pragma unroll
      for (int t = 0; t < 8; ++t) {
        int n = t * 16 + mrow;
        if (n < 120) {
          #pragma unroll
          for (int r2 = 0; r2 < 4; ++r2)
            __builtin_nontemporal_store(acc[t][r2], out + (atom0 + r2) * 120 + n);
        }
      }
    } else {
      #pragma unroll
      for (int t = 0; t < 8; ++t) {
        int n = t * 16 + mrow;
        if (n < 120) {
          #pragma unroll
          for (int r2 = 0; r2 < 4; ++r2)
            if (atom0 + r2 < natoms)
              __builtin_nontemporal_store(acc[t][r2], out + (atom0 + r2) * 120 + n);
        }
      }
    }

    tile = next;
  }
}

extern "C" void kernel_launch(void* const* d_in, const int* in_sizes, int n_in,
                              void* d_out, int out_size, void* d_ws, size_t ws_size,
                              hipStream_t stream) {
  const float* geom  = (const float*)d_in[0];
  const float* field = (const float*)d_in[1];
  const float* w000  = (const float*)d_in[2];
  const float* w011  = (const float*)d_in[3];
  const float* w101  = (const float*)d_in[4];
  const float* w110  = (const float*)d_in[5];
  const float* w112  = (const float*)d_in[6];
  const float* w202  = (const float*)d_in[7];
  const float* w211  = (const float*)d_in[8];
  const float* wl0   = (const float*)d_in[9];
  const float* wl1   = (const float*)d_in[10];
  const float* wl2   = (const float*)d_in[11];
  float* out = (float*)d_out;
  unsigned short* Bt = (unsigned short*)d_ws;   // 128*128 bf16 = 32 KB

  int natoms = in_sizes[0] / 120;

  build_B_kernel<<<dim3(128), dim3(128), 0, stream>>>(
      field, w000, w011, w101, w110, w112, w202, w211, wl0, wl1, wl2, Bt);

  int ntiles = (natoms + TM - 1) / TM;
  int nblk = ntiles < 1024 ? ntiles : 1024;   // 4 blocks/CU x 256 CU, persistent
  coupling_main<<<dim3(nblk), dim3(256), 0, stream>>>(geom, Bt, out, natoms, ntiles);
}

// Round 6
// 426.392 us; speedup vs baseline: 1.2301x; 1.2301x over previous
//
#include <hip/hip_runtime.h>

#define LDA 136   // padded B LDS row stride (bf16 elems)
#define TM  64    // atoms per tile

// W3J112 constant (3,3,5), already divided by sqrt(5). idx = i*15 + j*5 + k
__constant__ float W3J[45] = {
  0.f, 0.f, -0.18257418583505536f, 0.f, -0.31622776601683794f,
  0.f, 0.31622776601683794f, 0.f, 0.f, 0.f,
  0.31622776601683794f, 0.f, 0.f, 0.f, 0.f,
  0.f, 0.31622776601683794f, 0.f, 0.f, 0.f,
  0.f, 0.f, 0.36514837167011072f, 0.f, 0.f,
  0.f, 0.f, 0.f, 0.31622776601683794f, 0.f,
  0.31622776601683794f, 0.f, 0.f, 0.f, 0.f,
  0.f, 0.f, 0.f, 0.31622776601683794f, 0.f,
  0.f, 0.f, -0.18257418583505536f, 0.f, 0.31622776601683794f
};

__device__ __forceinline__ unsigned short f2bf(float f) {
  unsigned int u = __float_as_uint(f);
  u += 0x7FFFu + ((u >> 16) & 1u);   // round-to-nearest-even
  return (unsigned short)(u >> 16);
}

// Build Bt[n][k] = M[k][n] in bf16, padded to 128x128 with zeros.
// out[z,n] = sum_k geom[z,k] * M[k][n]
__global__ void build_B_kernel(
    const float* __restrict__ field,
    const float* __restrict__ w000, const float* __restrict__ w011,
    const float* __restrict__ w101, const float* __restrict__ w110,
    const float* __restrict__ w112, const float* __restrict__ w202,
    const float* __restrict__ w211, const float* __restrict__ wl0,
    const float* __restrict__ wl1,  const float* __restrict__ wl2,
    unsigned short* __restrict__ Bt)
{
  const float C0  = 0.02795084971874737f;   // sqrt(1/1280)
  const float C1  = 0.051031036307982884f;  // sqrt(3/1152)
  const float C2  = 0.09882117688026186f;   // sqrt(5/512)
  const float IS3 = 0.57735026918962576f;
  const float IS5 = 0.44721359549995794f;

  int n = blockIdx.x;    // output col 0..127
  int k = threadIdx.x;   // input row  0..127
  float val = 0.0f;

  if (n < 120 && k < 120) {
    if (n < 32) {
      int w = n;
      if (k < 32) {                 // g0 -> out0
        int u = k;
        float a = 0.f;
        for (int v = 0; v < 32; ++v) a += w000[u*1024 + v*32 + w] * field[v];
        val = C0 * a + wl0[u*32 + w] * 0.17677669529663689f;
      } else if (k < 80) {          // g1 -> out0 (110)
        int u = (k-32)/3, i = (k-32)%3;
        float a = 0.f;
        for (int v = 0; v < 16; ++v) a += w110[u*512 + v*32 + w] * field[32 + v*3 + i];
        val = C0 * IS3 * a;
      }                             // g2 -> out0 : zero
    } else if (n < 80) {
      int w = (n-32)/3, j = (n-32)%3;
      if (k < 32) {                 // g0 -> out1 (011)
        int u = k;
        float a = 0.f;
        for (int v = 0; v < 16; ++v) a += w011[u*256 + v*16 + w] * field[32 + v*3 + j];
        val = C1 * IS3 * a;
      } else if (k < 80) {          // g1 -> out1 (101 + residual), spatial-diagonal
        int u = (k-32)/3, i = (k-32)%3;
        if (i == j) {
          float a = 0.f;
          for (int v = 0; v < 32; ++v) a += w101[u*512 + v*16 + w] * field[v];
          val = C1 * IS3 * a + wl1[u*16 + w] * 0.25f;
        }
      } else {                      // g2 -> out1 (211 x W3J)
        int u = (k-80)/5, kk = (k-80)%5;
        float c0w = W3J[0*15 + j*5 + kk];
        float c1w = W3J[1*15 + j*5 + kk];
        float c2w = W3J[2*15 + j*5 + kk];
        float a = 0.f;
        for (int v = 0; v < 16; ++v) {
          float s = c0w*field[32+v*3+0] + c1w*field[32+v*3+1] + c2w*field[32+v*3+2];
          a += w211[u*256 + v*16 + w] * s;
        }
        val = C1 * a;
      }
    } else {
      int w = (n-80)/5, k2 = (n-80)%5;
      if (k >= 32 && k < 80) {      // g1 -> out2 (112 x W3J)
        int u = (k-32)/3, i = (k-32)%3;
        float c0w = W3J[i*15 + 0*5 + k2];
        float c1w = W3J[i*15 + 1*5 + k2];
        float c2w = W3J[i*15 + 2*5 + k2];
        float a = 0.f;
        for (int v = 0; v < 16; ++v) {
          float s = c0w*field[32+v*3+0] + c1w*field[32+v*3+1] + c2w*field[32+v*3+2];
          a += w112[u*128 + v*8 + w] * s;
        }
        val = C2 * a;
      } else if (k >= 80) {         // g2 -> out2 (202 + residual), spatial-diagonal
        int u = (k-80)/5, kk = (k-80)%5;
        if (kk == k2) {
          float a = 0.f;
          for (int v = 0; v < 32; ++v) a += w202[u*256 + v*8 + w] * field[v];
          val = C2 * IS5 * a + wl2[u*8 + w] * 0.35355339059327378f;
        }
      }                             // g0 -> out2 : zero
    }
  }
  Bt[n*128 + k] = f2bf(val);
}

typedef __attribute__((ext_vector_type(8))) __bf16 bf16x8;
typedef __attribute__((ext_vector_type(4))) float  f32x4;

// Prefetch A payload for tile TT into float4 LO[4]/HI[4] (leaves stale if TT>=ntiles: never used)
#define PREFETCH(TT, LO, HI) do {                                        \
    if ((TT) < ntiles) {                                                 \
      long long atom_ = (long long)(TT) * TM + rowin;                    \
      const float* ga_ = geom + atom_ * 120 + kq * 8;                    \
      bool full_ = ((long long)(TT) * TM + TM) <= (long long)natoms;     \
      bool ina_  = full_ || (atom_ < natoms);                            \
      _Pragma("unroll")                                                  \
      for (int ks_ = 0; ks_ < 4; ++ks_) {                                \
        bool pad_ = (ks_ == 3) && (kq == 3);                             \
        if (ina_ && !pad_) {                                             \
          LO[ks_] = ((const float4*)(ga_ + ks_ * 32))[0];                \
          HI[ks_] = ((const float4*)(ga_ + ks_ * 32))[1];                \
        } else { LO[ks_] = f0; HI[ks_] = f0; }                           \
      }                                                                  \
    }                                                                    \
  } while (0)

// Convert payload, MFMA against LDS B, store tile (plain stores: L2 write-combines)
#define COMPUTE_STORE(TT, LO, HI) do {                                   \
    bf16x8 af_[4];                                                       \
    _Pragma("unroll")                                                    \
    for (int ks_ = 0; ks_ < 4; ++ks_) {                                  \
      uint4 pk_;                                                         \
      pk_.x = ((unsigned)f2bf(LO[ks_].y) << 16) | f2bf(LO[ks_].x);       \
      pk_.y = ((unsigned)f2bf(LO[ks_].w) << 16) | f2bf(LO[ks_].z);       \
      pk_.z = ((unsigned)f2bf(HI[ks_].y) << 16) | f2bf(HI[ks_].x);       \
      pk_.w = ((unsigned)f2bf(HI[ks_].w) << 16) | f2bf(HI[ks_].z);       \
      af_[ks_] = __builtin_bit_cast(bf16x8, pk_);                        \
    }                                                                    \
    f32x4 acc_[8];                                                       \
    _Pragma("unroll")                                                    \
    for (int t_ = 0; t_ < 8; ++t_) acc_[t_] = (f32x4){0.f,0.f,0.f,0.f};  \
    _Pragma("unroll")                                                    \
    for (int ks_ = 0; ks_ < 4; ++ks_) {                                  \
      _Pragma("unroll")                                                  \
      for (int t_ = 0; t_ < 8; ++t_) {                                   \
        bf16x8 bf_ = __builtin_bit_cast(bf16x8,                          \
            *(const uint4*)(brow + t_ * 16 * LDA + ks_ * 32));           \
        acc_[t_] = __builtin_amdgcn_mfma_f32_16x16x32_bf16(af_[ks_], bf_, acc_[t_], 0, 0, 0); \
      }                                                                  \
    }                                                                    \
    long long atom0_ = (long long)(TT) * TM + wave * 16 + kq * 4;        \
    if ((long long)(TT) * TM + TM <= (long long)natoms) {                \
      _Pragma("unroll")                                                  \
      for (int t_ = 0; t_ < 8; ++t_) {                                   \
        int n_ = t_ * 16 + mrow;                                         \
        if (n_ < 120) {                                                  \
          _Pragma("unroll")                                              \
          for (int r_ = 0; r_ < 4; ++r_)                                 \
            out[(atom0_ + r_) * 120 + n_] = acc_[t_][r_];                \
        }                                                                \
      }                                                                  \
    } else {                                                             \
      _Pragma("unroll")                                                  \
      for (int t_ = 0; t_ < 8; ++t_) {                                   \
        int n_ = t_ * 16 + mrow;                                         \
        if (n_ < 120) {                                                  \
          _Pragma("unroll")                                              \
          for (int r_ = 0; r_ < 4; ++r_)                                 \
            if (atom0_ + r_ < natoms)                                    \
              out[(atom0_ + r_) * 120 + n_] = acc_[t_][r_];              \
        }                                                                \
      }                                                                  \
    }                                                                    \
  } while (0)

// out(500000x120) = geom(500000x120) @ M(120x120), bf16 MFMA 16x16x32, fp32 accum.
// v5: persistent blocks (4/CU), B in LDS once, NO barriers in loop,
//     2-deep A prefetch (double-buffered payload, static indexing),
//     PLAIN scalar stores (v4's nontemporal scalar stores caused partial-line
//     RMW: FETCH 465MB / WRITE 389MB vs ideal 240/240 — measured).
__global__ __launch_bounds__(256, 4) void coupling_main(
    const float* __restrict__ geom, const unsigned short* __restrict__ Btg,
    float* __restrict__ out, int natoms, int ntiles)
{
  __shared__ alignas(16) unsigned short Bl[128 * LDA];   // 34816 B

  const int tid  = threadIdx.x;
  const int lane = tid & 63;
  const int wave = tid >> 6;
  const int mrow = lane & 15;   // A row / B col within 16-tile
  const int kq   = lane >> 4;   // k-quad

  // stage B (128x128 bf16) into LDS once; L2-hot across blocks
  #pragma unroll
  for (int r = 0; r < 8; ++r) {
    int g   = tid + r * 256;        // 0..2047 groups of 8 bf16
    int row = g >> 4;
    int col = (g & 15) * 8;
    uint4 v = ((const uint4*)Btg)[g];
    *((uint4*)&Bl[row * LDA + col]) = v;
  }

  const int rowin = wave * 16 + mrow;   // row within tile, 0..63
  const int s = gridDim.x;
  const float4 f0 = make_float4(0.f, 0.f, 0.f, 0.f);

  float4 p0lo[4], p0hi[4];   // payload buffer 0
  float4 p1lo[4], p1hi[4];   // payload buffer 1

  int t = blockIdx.x;
  PREFETCH(t,     p0lo, p0hi);   // in flight across the B barrier
  PREFETCH(t + s, p1lo, p1hi);

  __syncthreads();   // B tile visible

  const unsigned short* brow = &Bl[mrow * LDA + kq * 8];

  while (true) {
    // phase 0: consume payload0, refill for t+2s
    if (t >= ntiles) break;
    {
      // copy payload to locals so PREFETCH can overwrite without WAR on the cvt
      float4 lo[4], hi[4];
      #pragma unroll
      for (int i = 0; i < 4; ++i) { lo[i] = p0lo[i]; hi[i] = p0hi[i]; }
      PREFETCH(t + 2 * s, p0lo, p0hi);
      COMPUTE_STORE(t, lo, hi);
    }
    t += s;

    // phase 1: consume payload1, refill for t+2s (== original t+3s)
    if (t >= ntiles) break;
    {
      float4 lo[4], hi[4];
      #pragma unroll
      for (int i = 0; i < 4; ++i) { lo[i] = p1lo[i]; hi[i] = p1hi[i]; }
      PREFETCH(t + 2 * s, p1lo, p1hi);
      COMPUTE_STORE(t, lo, hi);
    }
    t += s;
  }
}

extern "C" void kernel_launch(void* const* d_in, const int* in_sizes, int n_in,
                              void* d_out, int out_size, void* d_ws, size_t ws_size,
                              hipStream_t stream) {
  const float* geom  = (const float*)d_in[0];
  const float* field = (const float*)d_in[1];
  const float* w000  = (const float*)d_in[2];
  const float* w011  = (const float*)d_in[3];
  const float* w101  = (const float*)d_in[4];
  const float* w110  = (const float*)d_in[5];
  const float* w112  = (const float*)d_in[6];
  const float* w202  = (const float*)d_in[7];
  const float* w211  = (const float*)d_in[8];
  const float* wl0   = (const float*)d_in[9];
  const float* wl1   = (const float*)d_in[10];
  const float* wl2   = (const float*)d_in[11];
  float* out = (float*)d_out;
  unsigned short* Bt = (unsigned short*)d_ws;   // 128*128 bf16 = 32 KB

  int natoms = in_sizes[0] / 120;

  build_B_kernel<<<dim3(128), dim3(128), 0, stream>>>(
      field, w000, w011, w101, w110, w112, w202, w211, wl0, wl1, wl2, Bt);

  int ntiles = (natoms + TM - 1) / TM;
  int nblk = ntiles < 1024 ? ntiles : 1024;   // 4 blocks/CU x 256 CU, persistent
  coupling_main<<<dim3(nblk), dim3(256), 0, stream>>>(geom, Bt, out, natoms, ntiles);
}